// Round 1
// baseline (153.282 us; speedup 1.0000x reference)
//
#include <hip/hip_runtime.h>

#define L_SIG 65536
#define NBATCH 16
#define M_BLK 1024            // positions per block
#define SCOPY 1288            // halfs per shifted signal copy (1280 data + 8 pad)

typedef _Float16 half8 __attribute__((ext_vector_type(8)));
typedef float f32x16 __attribute__((ext_vector_type(16)));

// ---------------------------------------------------------------------------
// CWT real part via MFMA (layout validated in round 4):
//   out[(n*32+s)*65536 + h] = sum_k sig[n][h+k-128] * w[s][k]
//   w[s][k] = exp(-0.5 t^2) * cos(2*pi*6*t/scale), t=(k-128)/scale, scale=1+s
//
// Block: 256 thr (4 waves), one batch n, 1024 positions, all 32 scales.
// GEMM view: M=1024 (positions), N=32 (scales), K=256 (taps), fp16 in/fp32 acc.
// mfma_f32_32x32x16_f16: A[m=lane&31][k=(lane>>5)*8+j], B likewise,
// D col=lane&31 (scale), row=(reg&3)+8*(reg>>2)+4*(lane>>5) (position).
//
// LDS: w_lds[32][256] fp16 (16B chunks XOR-swizzled by o&7 so B-reads spread
// banks); s_lds = 8 shifted copies of the signal tile (copy c shifted by c)
// so every A-read is a 16B-aligned ds_read_b128; tw = per-wave 32x33 f32
// transpose buffer (stride 33 == 1 mod 32: writes/reads 2-way/free).
//
// R1 change: epilogue split into two 32-position passes (acc0 then acc1)
// reusing ONE 32x33 tw region per wave -> tw 33280B -> 16896B, total LDS
// 70272 -> 53888 B -> 3 blocks/CU instead of 2 (12 waves/CU, 3/SIMD).
// Kernel was latency-bound (HBM ~21us, LDS ~19us, MFMA ~2us vs 72us wall);
// +50% occupancy attacks the latency gaps. WAR on tw between passes is safe:
// same-wave DS ops process in order, and the compiler cannot reorder the
// aliasing tw writes ahead of the tw reads.
// Chunk c (4x): wave w computes positions c*256+w*64..+63 (2 M-tiles of 32),
// 16 K-steps; A-frag identity af(mt,ks)==af(mt+1,ks-2) -> ring of 4, 18 loads.
// B-frags (16) hoisted to registers once per block.
// No __syncthreads after staging (tw is per-wave; s_waitcnt lgkmcnt(0) only).
// ---------------------------------------------------------------------------
__global__ __launch_bounds__(256, 3) void cwt_mfma(
        const float* __restrict__ sig,
        float* __restrict__ out) {

    __shared__ __align__(16) _Float16 w_lds[32 * 256];   // 16384 B
    __shared__ __align__(16) _Float16 s_lds[8 * SCOPY];  // 20608 B
    __shared__ __align__(16) float    tw[4][32 * 33];    // 16896 B

    const int tid = threadIdx.x;
    const int n   = blockIdx.y;
    const int h0  = blockIdx.x * M_BLK;

    // ---- generate wavelet bank into w_lds (fp16, chunk-swizzled) ----
    {
        int o  = tid >> 3;                 // scale 0..31
        int k0 = (tid & 7) * 32;           // 32 taps per thread
        float scale = 1.0f + (float)o;
        float inv_s = 1.0f / scale;
        float pcoef = 37.699111843077518861f * inv_s * inv_s; // 2*pi*6/scale^2
        #pragma unroll
        for (int cc = 0; cc < 4; ++cc) {
            union { _Float16 h[8]; uint4 u4; } pk;
            #pragma unroll
            for (int j = 0; j < 8; ++j) {
                float km = (float)(k0 + cc * 8 + j) - 128.0f;
                float t = km * inv_s;
                float env = __expf(-0.5f * t * t);
                pk.h[j] = (_Float16)(env * __cosf(pcoef * km));
            }
            int cidx = (k0 >> 3) + cc;     // logical 16B chunk 0..31
            *(uint4*)&w_lds[o * 256 + ((cidx ^ (o & 7)) << 3)] = pk.u4;
        }
    }

    // ---- stage 8 shifted fp16 copies of signal tile [h0-128, h0+1152) ----
    {
        const float* sp = sig + (size_t)n * L_SIG;
        #pragma unroll
        for (int c = 0; c < 8; ++c) {
            for (int xi = tid; xi < 640; xi += 256) {   // 640 u32 = 1280 halfs
                int x = xi * 2;
                int e = h0 - 128 + c + x;
                float v0 = ((unsigned)e       < L_SIG) ? sp[e]     : 0.0f;
                float v1 = ((unsigned)(e + 1) < L_SIG) ? sp[e + 1] : 0.0f;
                union { _Float16 h[2]; unsigned u; } p;
                p.h[0] = (_Float16)v0;
                p.h[1] = (_Float16)v1;
                *(unsigned*)&s_lds[c * SCOPY + x] = p.u;
            }
        }
    }
    __syncthreads();

    const int w  = tid >> 6;
    const int l  = tid & 63;
    const int m5 = l & 31;     // A row m / B col n / D col (scale)
    const int hk = l >> 5;     // k-half selector

    // ---- hoist all 16 B-fragments to registers ----
    half8 bf[16];
    #pragma unroll
    for (int ks = 0; ks < 16; ++ks) {
        int cidx = (ks << 1) + hk;
        bf[ks] = *(const half8*)&w_lds[m5 * 256 + ((cidx ^ (m5 & 7)) << 3)];
    }

    // A-read base: copy (l&7), x = w*64 + (l&24) + hk*8 (+ c*256 + u*16)
    const int abase = (l & 7) * SCOPY + (l & 24) + (hk << 3) + w * 64;
    float* twp = &tw[w][0];
    const size_t obase0 = ((size_t)(n * 32) << 16) + (size_t)(h0 + w * 64);

    #pragma unroll 1
    for (int c = 0; c < 4; ++c) {
        const _Float16* ap = &s_lds[abase + c * 256];
        f32x16 acc0 = {};
        f32x16 acc1 = {};
        half8 af[4];
        #pragma unroll
        for (int u = 0; u < 4; ++u)
            af[u] = *(const half8*)&ap[u * 16];

        #pragma unroll
        for (int ks = 0; ks < 16; ++ks) {
            acc0 = __builtin_amdgcn_mfma_f32_32x32x16_f16(af[ks & 3],
                                                          bf[ks], acc0, 0, 0, 0);
            acc1 = __builtin_amdgcn_mfma_f32_32x32x16_f16(af[(ks + 2) & 3],
                                                          bf[ks], acc1, 0, 0, 0);
            if (ks < 14)
                af[ks & 3] = *(const half8*)&ap[(ks + 4) * 16];
        }

        // ---- epilogue: two 32-position passes through one 32x33 tw region ----
        const size_t ob = obase0 + (size_t)(c * 256);
        #pragma unroll
        for (int p = 0; p < 2; ++p) {
            const f32x16& a = p ? acc1 : acc0;
            #pragma unroll
            for (int r = 0; r < 16; ++r) {
                int row = (r & 3) + ((r >> 2) << 3) + (hk << 2);   // 0..31
                twp[m5 * 33 + row] = a[r];
            }
            asm volatile("s_waitcnt lgkmcnt(0)" ::: "memory");
            // 16 stores, each 2 x 128B segments (lanes 0-31: scale t,
            // lanes 32-63: scale t+16), positions p*32 + m5
            #pragma unroll
            for (int t = 0; t < 16; ++t) {
                int se = t + (hk << 4);
                out[ob + (size_t)(p * 32) + ((size_t)se << 16) + m5] =
                    twp[se * 33 + m5];
            }
        }
    }
}

extern "C" void kernel_launch(void* const* d_in, const int* in_sizes, int n_in,
                              void* d_out, int out_size, void* d_ws, size_t ws_size,
                              hipStream_t stream) {
    const float* sig = (const float*)d_in[0];
    float* out = (float*)d_out;
    cwt_mfma<<<dim3(L_SIG / M_BLK, NBATCH), dim3(256), 0, stream>>>(sig, out);
}

// Round 2
// 142.709 us; speedup vs baseline: 1.0741x; 1.0741x over previous
//
#include <hip/hip_runtime.h>

#define L_SIG 65536
#define NBATCH 16
#define M_BLK 1024            // positions per block
#define SCOPY 1288            // halfs per shifted signal copy (1280 data + 8 pad)

typedef _Float16 half8 __attribute__((ext_vector_type(8)));
typedef float f32x16 __attribute__((ext_vector_type(16)));

// ---------------------------------------------------------------------------
// CWT real part via MFMA:
//   out[(n*32+s)*65536 + h] = sum_k sig[n][h+k-128] * w[s][k]
//   w[s][k] = exp(-0.5 t^2) * cos(2*pi*6*t/scale), t=(k-128)/scale, scale=1+s
//
// Block: 256 thr (4 waves), one batch n, 1024 positions, all 32 scales.
// GEMM view (R2, operands SWAPPED vs R0/R1): M=32 (scales), N=positions,
// K=256 (taps). mfma_f32_32x32x16_f16 with A = wavelet, B = signal:
//   A[m=lane&31][k=(lane>>5)*8+j]  -> lane holds wavelet[scale=lane&31][...]
//   B[k][n=lane&31]                -> lane holds sig[pos = base+lane&31 + k]
//   D col = lane&31 = POSITION (contiguous), row = scale
//       = (reg&3)+8*(reg>>2)+4*(lane>>5)
// => accumulators store DIRECTLY to global as 2x128B coalesced segments.
// The entire LDS transpose epilogue (tw buffer, 2x lgkmcnt(0) drains per
// chunk, 1024 ds ops per block) from R0/R1 is deleted. That epilogue was
// ~55% of block LDS traffic and its full drains + "memory" asm barriers
// serialized every chunk (R1 showed occupancy was NOT the limiter).
//
// LDS now: w_lds[32][256] fp16 (16B chunks XOR-swizzled by scale&7) +
// s_lds = 8 shifted copies of the signal tile (copy c shifted by c) so every
// B-read is a 16B-aligned ds_read_b128 (copy = pos&7). Total 36,992 B.
// Wavelet A-frags (16) hoisted to registers once per block (reused by all
// 4 chunks x 2 tiles). Per chunk: 2 accumulators (2 position tiles of 32),
// 16 K-steps, 2 ds_read_b128 per step (double-buffered), 32 direct stores.
// ---------------------------------------------------------------------------
__global__ __launch_bounds__(256, 3) void cwt_mfma(
        const float* __restrict__ sig,
        float* __restrict__ out) {

    __shared__ __align__(16) _Float16 w_lds[32 * 256];   // 16384 B
    __shared__ __align__(16) _Float16 s_lds[8 * SCOPY];  // 20608 B

    const int tid = threadIdx.x;
    const int n   = blockIdx.y;
    const int h0  = blockIdx.x * M_BLK;

    // ---- generate wavelet bank into w_lds (fp16, chunk-swizzled) ----
    {
        int o  = tid >> 3;                 // scale 0..31
        int k0 = (tid & 7) * 32;           // 32 taps per thread
        float scale = 1.0f + (float)o;
        float inv_s = 1.0f / scale;
        float pcoef = 37.699111843077518861f * inv_s * inv_s; // 2*pi*6/scale^2
        #pragma unroll
        for (int cc = 0; cc < 4; ++cc) {
            union { _Float16 h[8]; uint4 u4; } pk;
            #pragma unroll
            for (int j = 0; j < 8; ++j) {
                float km = (float)(k0 + cc * 8 + j) - 128.0f;
                float t = km * inv_s;
                float env = __expf(-0.5f * t * t);
                pk.h[j] = (_Float16)(env * __cosf(pcoef * km));
            }
            int cidx = (k0 >> 3) + cc;     // logical 16B chunk 0..31
            *(uint4*)&w_lds[o * 256 + ((cidx ^ (o & 7)) << 3)] = pk.u4;
        }
    }

    // ---- stage 8 shifted fp16 copies of signal tile [h0-128, h0+1152) ----
    {
        const float* sp = sig + (size_t)n * L_SIG;
        #pragma unroll
        for (int c = 0; c < 8; ++c) {
            for (int xi = tid; xi < 640; xi += 256) {   // 640 u32 = 1280 halfs
                int x = xi * 2;
                int e = h0 - 128 + c + x;
                float v0 = ((unsigned)e       < L_SIG) ? sp[e]     : 0.0f;
                float v1 = ((unsigned)(e + 1) < L_SIG) ? sp[e + 1] : 0.0f;
                union { _Float16 h[2]; unsigned u; } p;
                p.h[0] = (_Float16)v0;
                p.h[1] = (_Float16)v1;
                *(unsigned*)&s_lds[c * SCOPY + x] = p.u;
            }
        }
    }
    __syncthreads();

    const int w  = tid >> 6;
    const int l  = tid & 63;
    const int m5 = l & 31;     // A row (scale) / B col (position) / D col
    const int hk = l >> 5;     // k-half selector

    // ---- hoist all 16 wavelet A-fragments to registers ----
    half8 af[16];
    #pragma unroll
    for (int ks = 0; ks < 16; ++ks) {
        int cidx = (ks << 1) + hk;
        af[ks] = *(const half8*)&w_lds[m5 * 256 + ((cidx ^ (m5 & 7)) << 3)];
    }

    // B-read base: copy (m5&7), x = w*64 + (m5&24) + hk*8 (+ c*256 + tile*32
    // + ks*16). All terms multiple of 8 halfs -> aligned ds_read_b128.
    const int bbase = (m5 & 7) * SCOPY + (m5 & 24) + (hk << 3) + w * 64;
    const size_t obase = ((size_t)(n * 32) << 16) + (size_t)(h0 + w * 64);

    #pragma unroll 1
    for (int c = 0; c < 4; ++c) {
        const _Float16* bp = &s_lds[bbase + c * 256];
        f32x16 acc0 = {};
        f32x16 acc1 = {};
        half8 b0 = *(const half8*)&bp[0];        // tile 0 (positions +0..31)
        half8 b1 = *(const half8*)&bp[32];       // tile 1 (positions +32..63)

        #pragma unroll
        for (int ks = 0; ks < 16; ++ks) {
            half8 nb0, nb1;
            if (ks < 15) {
                nb0 = *(const half8*)&bp[(ks + 1) * 16];
                nb1 = *(const half8*)&bp[(ks + 1) * 16 + 32];
            }
            acc0 = __builtin_amdgcn_mfma_f32_32x32x16_f16(af[ks], b0, acc0, 0, 0, 0);
            acc1 = __builtin_amdgcn_mfma_f32_32x32x16_f16(af[ks], b1, acc1, 0, 0, 0);
            b0 = nb0;
            b1 = nb1;
        }

        // ---- direct coalesced stores from accumulators ----
        // reg r -> scale row (r&3)+8*(r>>2)+4*hk, lanes m5 -> 32 contiguous
        // positions: each store = 2 x 128B segments (hk=0: row, hk=1: row+4).
        const size_t ob = obase + (size_t)(c * 256);
        #pragma unroll
        for (int r = 0; r < 16; ++r) {
            size_t po = ob + ((size_t)((r & 3) + ((r >> 2) << 3) + (hk << 2)) << 16);
            out[po + m5]      = acc0[r];
            out[po + 32 + m5] = acc1[r];
        }
    }
}

extern "C" void kernel_launch(void* const* d_in, const int* in_sizes, int n_in,
                              void* d_out, int out_size, void* d_ws, size_t ws_size,
                              hipStream_t stream) {
    const float* sig = (const float*)d_in[0];
    float* out = (float*)d_out;
    cwt_mfma<<<dim3(L_SIG / M_BLK, NBATCH), dim3(256), 0, stream>>>(sig, out);
}